// Round 4
// baseline (160.824 us; speedup 1.0000x reference)
//
#include <hip/hip_runtime.h>
#include <hip/hip_bf16.h>
#include <stdint.h>

#define KDIM 4096
#define NDIM 4096
#define MDIM 4096
#define BM 256
#define BN 256
#define BK 64

typedef __attribute__((ext_vector_type(8))) short bf16x8;
typedef __attribute__((ext_vector_type(4))) float f32x4;

// ---------- helpers ----------

__device__ __forceinline__ unsigned short bf16bits(float f) {
    union { float f; uint32_t u; } c; c.f = f;
    uint32_t u = c.u;
    uint32_t r = (u + 0x7fffu + ((u >> 16) & 1u)) >> 16;   // RNE
    return (unsigned short)r;
}

// Faithful FP4 E2M1 quant-dequant (matches reference float math).
__device__ __forceinline__ float fp4qd(float x) {
    float a = fabsf(x);
    if (a == 0.0f) return 0.0f;
    float e = floorf(log2f(a));
    float val;
    if (e < 0.0f) {                       // subnormal path
        float mant = fminf(fmaxf(rintf(a * 2.0f), 0.0f), 1.0f);
        val = mant * 0.5f;
    } else {
        float ec = fminf(e, 2.0f);
        float p  = exp2f(ec);             // exact: 1,2,4
        float mant = fminf(fmaxf(rintf((a / p - 1.0f) * 2.0f), 0.0f), 1.0f);
        val = (1.0f + 0.5f * mant) * p;
    }
    return (x < 0.0f) ? -val : val;
}

__device__ __forceinline__ void gld16(void* lds, const void* g) {
    __builtin_amdgcn_global_load_lds(
        (const __attribute__((address_space(1))) unsigned int*)g,
        (__attribute__((address_space(3))) unsigned int*)lds,
        16, 0, 0);
}

// ---------- kernel 1: weight quant-dequant -> bf16 ----------
__global__ __launch_bounds__(256) void wdeq_kernel(const float* __restrict__ W,
                                                   unsigned short* __restrict__ Wq) {
    int grp = blockIdx.x * 4 + (threadIdx.x >> 6);
    int l = threadIdx.x & 63;
    const float* gp = W + (size_t)grp * 128 + l * 2;
    float2 v = *(const float2*)gp;
    float am = fmaxf(fabsf(v.x), fabsf(v.y));
    #pragma unroll
    for (int s = 32; s; s >>= 1) am = fmaxf(am, __shfl_xor(am, s));
    float scale = (am == 0.0f) ? 1.0f : am / 6.0f;
    float q0 = fp4qd(v.x / scale) * scale;
    float q1 = fp4qd(v.y / scale) * scale;
    ushort2 o;
    o.x = bf16bits(q0);
    o.y = bf16bits(q1);
    *(ushort2*)(Wq + (size_t)grp * 128 + l * 2) = o;
}

// ---------- kernel 2: x f32 -> bf16 ----------
__global__ __launch_bounds__(256) void xcvt_kernel(const float* __restrict__ X,
                                                   unsigned short* __restrict__ Xb) {
    size_t i = (size_t)(blockIdx.x * 256 + threadIdx.x) * 4;
    float4 v = *(const float4*)(X + i);
    ushort4 o;
    o.x = bf16bits(v.x); o.y = bf16bits(v.y);
    o.z = bf16bits(v.z); o.w = bf16bits(v.w);
    *(ushort4*)(Xb + i) = o;
}

// ---------- kernel 3: 256x256 8-phase GEMM with one-phase-ahead ds_reads ----
// C = A @ B^T + bias. 8 waves (2M x 4N), per-wave 128x64, acc[8][4].
// LDS: [buf][op][slab(64 rows)][8KB], 128 KiB. Staging = 64-row slab via
// gld16, chunk-XOR swizzled (slot = kc ^ (row&7)); conflict-free ds_read_b128.
// Quadrants per tile: P1=(0,0) P2=(0,1) P3=(1,1) P4=(1,0).
// Fragment streams (single register array each, read one phase ahead):
//   aE=A-mh0 (read P7 for next-even-tile; consumed P1,P2)
//   aO=A-mh1 (read P2/P6; consumed P3,P4 / P7,P8)
//   bO=B-nh1 (read P1/P5; consumed P2,P3 / P6,P7)
//   bE=B-nh0 (wrap stream; read post-MFMA P4/P8; consumed P5,P8 / P1,P4)
// Counted lgkm waits: P1:4 P2:8 P3:8 P4:- P5:4 P6:8 P7:8 P8:- (FIFO-audited).
// Stage ledger (tile T2->buf0, T3->buf1): P2:A02 P3:B01 P4:A13+B23 (buf0),
// P6:A02 P7:B01 P8:A13+B23 (buf1). vmcnt: P2-end(8), P3-end(4), P6-end(2);
// every stage->drain gap >= 2 phases, every drain->read gap audited.

#define BAR()    __builtin_amdgcn_s_barrier()
#define LGKM(n)  asm volatile("s_waitcnt lgkmcnt(" #n ")" ::: "memory")
#define VM(n)    asm volatile("s_waitcnt vmcnt(" #n ")" ::: "memory")
#define SCH0()   __builtin_amdgcn_sched_barrier(0)
#define PRIO(x)  __builtin_amdgcn_s_setprio(x)

__global__ __launch_bounds__(512, 2) void gemm256(const unsigned short* __restrict__ A,
                                                  const unsigned short* __restrict__ B,
                                                  const float* __restrict__ bias,
                                                  float* __restrict__ C) {
    __shared__ __attribute__((aligned(16))) char smem[2][2][4][8192];
    char* sm = (char*)&smem[0][0][0][0];

    const int t = threadIdx.x;
    const int l = t & 63;
    const int w = __builtin_amdgcn_readfirstlane(t >> 6);  // 0..7
    const int wm = w >> 2;        // 0..1  (M half)
    const int wn = w & 3;         // 0..3  (N quarter)

    // bijective XCD swizzle (256 blocks, 8 XCDs)
    int bid = blockIdx.x;
    int swz = (bid & 7) * 32 + (bid >> 3);
    int brow = (swz >> 4) * BM;
    int bcol = (swz & 15) * BN;

    // ---- staging addresses (pre-swizzled global source, linear LDS dest) ----
    const int lr8  = l >> 3;                 // row in 8-row slab
    const int slot = l & 7;
    const int scol = (slot ^ lr8) << 3;      // swizzled source col (elements)
    const unsigned short* pA = A + (size_t)(brow + w * 8 + lr8) * KDIM + scol;
    const unsigned short* pB = B + (size_t)(bcol + w * 8 + lr8) * KDIM + scol;

#define STAGE64(b, op, slab, kt) do {                                          \
    const unsigned short* _s = ((op) ? pB : pA)                                \
        + (size_t)((slab) * 64) * KDIM + (size_t)(kt) * BK;                    \
    gld16(sm + (b) * 65536 + (op) * 32768 + (slab) * 8192 + w * 1024, _s);     \
} while (0)

    // ---- fragment read addressing ----
    const int fr  = l & 15;
    const int fq  = l >> 4;
    const int kx0 = ((fq    ) ^ (fr & 7)) << 4;   // ks=0 swizzled chunk byte
    const int kx1 = ((fq + 4) ^ (fr & 7)) << 4;   // ks=1
    const int frA = fr * 128;

#define RD_A(b, mh, arr) do {                                                   \
    const char* _p = sm + (b) * 65536 + wm * 16384 + (mh) * 8192 + frA;         \
    _Pragma("unroll")                                                           \
    for (int m = 0; m < 4; ++m) {                                               \
        arr[m][0] = *(const bf16x8*)(_p + m * 2048 + kx0);                      \
        arr[m][1] = *(const bf16x8*)(_p + m * 2048 + kx1);                      \
    }                                                                           \
} while (0)

#define RD_B(b, nh, arr) do {                                                   \
    const char* _p = sm + (b) * 65536 + 32768 + wn * 8192 + (nh) * 4096 + frA;  \
    _Pragma("unroll")                                                           \
    for (int n = 0; n < 2; ++n) {                                               \
        arr[n][0] = *(const bf16x8*)(_p + n * 2048 + kx0);                      \
        arr[n][1] = *(const bf16x8*)(_p + n * 2048 + kx1);                      \
    }                                                                           \
} while (0)

// ks-outer: 8 independent MFMAs then 8 dependent (breaks dep-chain stalls)
#define MM(mh, nh, A_, B_)                                                      \
    _Pragma("unroll")                                                           \
    for (int ks = 0; ks < 2; ++ks)                                              \
        _Pragma("unroll")                                                       \
        for (int m = 0; m < 4; ++m)                                             \
            _Pragma("unroll")                                                   \
            for (int n = 0; n < 2; ++n)                                         \
                acc[(mh) * 4 + m][(nh) * 2 + n] =                               \
                    __builtin_amdgcn_mfma_f32_16x16x32_bf16(                    \
                        A_[m][ks], B_[n][ks], acc[(mh) * 4 + m][(nh) * 2 + n],  \
                        0, 0, 0);

    f32x4 acc[8][4];
    #pragma unroll
    for (int m = 0; m < 8; ++m)
        #pragma unroll
        for (int n = 0; n < 4; ++n)
            acc[m][n] = f32x4{0.f, 0.f, 0.f, 0.f};

    bf16x8 aE[4][2], aO[4][2], bE[2][2], bO[2][2];

    // ---- prologue: stage tile0 (buf0) + tile1 (buf1) fully; clean FIFO ----
    STAGE64(0, 0, 0, 0); STAGE64(0, 0, 2, 0); STAGE64(0, 1, 0, 0); STAGE64(0, 1, 1, 0);
    STAGE64(0, 0, 1, 0); STAGE64(0, 0, 3, 0); STAGE64(0, 1, 2, 0); STAGE64(0, 1, 3, 0);
    STAGE64(1, 0, 0, 1); STAGE64(1, 0, 2, 1); STAGE64(1, 1, 0, 1); STAGE64(1, 1, 1, 1);
    STAGE64(1, 0, 1, 1); STAGE64(1, 0, 3, 1); STAGE64(1, 1, 2, 1); STAGE64(1, 1, 3, 1);
    VM(0);
    BAR();
    RD_A(0, 0, aE);          // T0.A0 (consumed P1,P2)
    RD_B(0, 0, bE);          // T0.B0 (consumed P1,P4)

    // ---- main loop: iter computes tiles 2it (buf0, P1-4), 2it+1 (buf1, P5-8)
    for (int it = 0; it < 32; ++it) {
        const int k2 = (2 * it + 2) & 63;   // next even tile -> buf0
        const int k3 = (2 * it + 3) & 63;   // next odd tile  -> buf1

        // P1: pre-read T0.B1->bO
        SCH0();
        RD_B(0, 1, bO);
        BAR(); LGKM(4); SCH0();
        PRIO(1); MM(0, 0, aE, bE); PRIO(0);
        BAR();
        // P2: pre-read T0.A1->aO ; stage T2.A slabs 0,2
        SCH0();
        RD_A(0, 1, aO);
        STAGE64(0, 0, 0, k2); STAGE64(0, 0, 2, k2);
        BAR(); LGKM(8); SCH0();
        PRIO(1); MM(0, 1, aE, bO); PRIO(0);
        VM(8);
        BAR();
        // P3: pre-read T1.A0->aE ; stage T2.B slabs 0,1
        SCH0();
        RD_A(1, 0, aE);
        STAGE64(0, 1, 0, k2); STAGE64(0, 1, 1, k2);
        BAR(); LGKM(8); SCH0();
        PRIO(1); MM(1, 1, aO, bO); PRIO(0);
        VM(4);
        BAR();
        // P4: stage T2.A slabs 1,3 + T2.B slabs 2,3 ; post-read T1.B0->bE
        SCH0();
        STAGE64(0, 0, 1, k2); STAGE64(0, 0, 3, k2);
        STAGE64(0, 1, 2, k2); STAGE64(0, 1, 3, k2);
        BAR(); SCH0();
        PRIO(1); MM(1, 0, aO, bE); PRIO(0);
        RD_B(1, 0, bE);
        BAR();
        // P5: pre-read T1.B1->bO
        SCH0();
        RD_B(1, 1, bO);
        BAR(); LGKM(4); SCH0();
        PRIO(1); MM(0, 0, aE, bE); PRIO(0);
        BAR();
        // P6: pre-read T1.A1->aO ; stage T3.A slabs 0,2
        SCH0();
        RD_A(1, 1, aO);
        STAGE64(1, 0, 0, k3); STAGE64(1, 0, 2, k3);
        BAR(); LGKM(8); SCH0();
        PRIO(1); MM(0, 1, aE, bO); PRIO(0);
        VM(2);
        BAR();
        // P7: pre-read T2.A0->aE ; stage T3.B slabs 0,1
        SCH0();
        RD_A(0, 0, aE);
        STAGE64(1, 1, 0, k3); STAGE64(1, 1, 1, k3);
        BAR(); LGKM(8); SCH0();
        PRIO(1); MM(1, 1, aO, bO); PRIO(0);
        BAR();
        // P8: stage T3.A slabs 1,3 + T3.B slabs 2,3 ; post-read T2.B0->bE
        SCH0();
        STAGE64(1, 0, 1, k3); STAGE64(1, 0, 3, k3);
        STAGE64(1, 1, 2, k3); STAGE64(1, 1, 3, k3);
        BAR(); SCH0();
        PRIO(1); MM(1, 0, aO, bE); PRIO(0);
        RD_B(0, 0, bE);
        BAR();
    }

    // ---- epilogue: C[row][col] = acc + bias[col] ----
    float bb[4];
    #pragma unroll
    for (int n = 0; n < 4; ++n) bb[n] = bias[bcol + wn * 64 + n * 16 + fr];
    #pragma unroll
    for (int mi = 0; mi < 8; ++mi) {
        #pragma unroll
        for (int q = 0; q < 4; ++q) {
            int row = brow + wm * 128 + mi * 16 + fq * 4 + q;
            float* crow = C + (size_t)row * NDIM + bcol + wn * 64;
            #pragma unroll
            for (int n = 0; n < 4; ++n)
                crow[n * 16 + fr] = acc[mi][n][q] + bb[n];
        }
    }
}

// ---------- launch ----------
extern "C" void kernel_launch(void* const* d_in, const int* in_sizes, int n_in,
                              void* d_out, int out_size, void* d_ws, size_t ws_size,
                              hipStream_t stream) {
    const float* x = (const float*)d_in[0];
    const float* w = (const float*)d_in[1];
    const float* b = (const float*)d_in[2];
    float* out = (float*)d_out;

    unsigned short* xb = (unsigned short*)d_ws;                         // 32 MB
    unsigned short* wq = xb + (size_t)NDIM * KDIM;                      // 32 MB

    xcvt_kernel<<<MDIM * KDIM / 4 / 256, 256, 0, stream>>>(x, xb);
    wdeq_kernel<<<NDIM * (KDIM / 128) / 4, 256, 0, stream>>>(w, wq);
    gemm256<<<(MDIM / BM) * (NDIM / BN), 512, 0, stream>>>(xb, wq, b, out);
}